// Round 5
// baseline (350.342 us; speedup 1.0000x reference)
//
#include <hip/hip_runtime.h>

#define NB 1000000
#define NA 40
#define TILE 256
#define G 4
#define SPB (TILE * G)                    // 1024 samples per block
#define NBLK ((NB + SPB - 1) / SPB)       // 977 blocks -> one generation at 4 blocks/CU
#define NEG_LN2_OVER_A (-0.017328679513998632f)  // -ln(2)/40, folded into weights

// R5 structure: 4 consecutive 256-sample tiles per block, software-pipelined.
//  - R1/R3/R4 established the kernel is NOT concurrency-limited: occupancy
//    36->54% left BW pinned at 2.75 TB/s total (1.37 HBM + ~1.37 LLC) and
//    dur at ~116 us. The memory path is saturated for the old pattern.
//  - Old pattern: each block read targets as 40 scattered 1 KB chunks at
//    4 MB stride (~4000 concurrent granules device-wide). Now each block
//    reads 40 x 4 KB sequential runs -> better DRAM page locality.
//  - Pipeline: next-tile targets prefetched into regs UNDER compute (their
//    consumer is the post-compute LDS pack, so the compiler cannot sink the
//    loads); next-tile inputs issued just before the barrier, which the
//    compiler's vmcnt(0) drain then COMPLETES -> compute never waits on xv.
//  - 977 atomics instead of 3907 (was already not the wall; now trivial).
// Tripwire: VGPR<=60 => prefetch defeated => escalate to global_load_lds.
__global__ __launch_bounds__(256, 4) void focal_loss_kernel(
    const float* __restrict__ inputs,    // [NB, NA] f32
    const int*   __restrict__ targets,   // [NA, NB] i32 in {0,1}
    const float* __restrict__ attr_w,    // [NA] f32
    float* __restrict__ out)             // [1] f32 (pre-zeroed)
{
    __shared__ unsigned int s_t[2][NA * 65];   // double-buffered [40][65] u32
    __shared__ float s_aw[NA];
    __shared__ float s_red[TILE / 64];

    const int t  = threadIdx.x;
    const int B0 = blockIdx.x * SPB;

    if (t < NA) s_aw[t] = attr_w[t] * NEG_LN2_OVER_A;

    float acc = 0.0f;

    if (blockIdx.x != NBLK - 1) {
        // ================= full block: 4 full tiles, pipelined ==============
        int4   v[10];
        float4 xv[10];
        const float4* in4 = (const float4*)inputs;

        // ---- prologue: tile 0 targets + inputs, pack, barrier ----
        #pragma unroll
        for (int j = 0; j < 10; ++j) {
            const int q = t + TILE * j, a = q >> 6, t4 = q & 63;
            v[j] = *(const int4*)(targets + (size_t)a * NB + (B0 + 4 * t4));
        }
        #pragma unroll
        for (int j = 0; j < 10; ++j)
            xv[j] = in4[(size_t)B0 * 10 + t + TILE * j];
        #pragma unroll
        for (int j = 0; j < 10; ++j) {
            const int q = t + TILE * j, a = q >> 6, t4 = q & 63;
            s_t[0][a * 65 + t4] = (unsigned)(v[j].x & 1)        | ((unsigned)(v[j].y & 1) << 8)
                                | ((unsigned)(v[j].z & 1) << 16) | ((unsigned)(v[j].w & 1) << 24);
        }
        __syncthreads();

        #pragma unroll
        for (int g = 0; g < G; ++g) {
            const int bt_next = B0 + TILE * (g + 1);

            // ---- prefetch next-tile targets (consumed after compute) ----
            if (g < G - 1) {
                #pragma unroll
                for (int j = 0; j < 10; ++j) {
                    const int q = t + TILE * j, a = q >> 6, t4 = q & 63;
                    v[j] = *(const int4*)(targets + (size_t)a * NB + (bt_next + 4 * t4));
                }
            }

            // ---- compute tile g (long VALU phase hides the v[] loads) ----
            const unsigned char* st8 = (const unsigned char*)s_t[g & 1];
            #pragma unroll
            for (int j = 0; j < 10; ++j) {
                const int f = t + TILE * j;
                const int s = f / 10;            // sample within tile
                const int r = 4 * (f - s * 10);  // attr base (0,4,...,36)
                const float xs[4] = {xv[j].x, xv[j].y, xv[j].z, xv[j].w};
                #pragma unroll
                for (int k = 0; k < 4; ++k) {
                    const float x   = xs[k];
                    const float om  = 1.0f - x;
                    const float w   = s_aw[r + k] * (om * om);   // -ln2/40*aw*(1-x)^2
                    const float p   = fmaxf(x,  1e-12f);
                    const float q0  = fmaxf(om, 1e-12f);
                    const float sel = st8[(r + k) * 260 + s] ? p : q0;
                    acc = fmaf(w, __log2f(sel), acc);            // w<0, log2<=0 -> positive
                }
            }

            if (g < G - 1) {
                // next-tile inputs: issued here, completed by the barrier drain
                #pragma unroll
                for (int j = 0; j < 10; ++j)
                    xv[j] = in4[(size_t)bt_next * 10 + t + TILE * j];
                // pack prefetched targets into the other LDS buffer
                #pragma unroll
                for (int j = 0; j < 10; ++j) {
                    const int q = t + TILE * j, a = q >> 6, t4 = q & 63;
                    s_t[(g + 1) & 1][a * 65 + t4] =
                          (unsigned)(v[j].x & 1)        | ((unsigned)(v[j].y & 1) << 8)
                        | ((unsigned)(v[j].z & 1) << 16) | ((unsigned)(v[j].w & 1) << 24);
                }
                __syncthreads();
            }
        }
    } else {
        // ================= tail block (576 valid samples): guarded ==========
        for (int g = 0; g < G; ++g) {
            const int bt = B0 + TILE * g;
            if (bt >= NB) break;               // uniform across block
            __syncthreads();                   // protect s_t[0] reuse (and s_aw)
            #pragma unroll
            for (int j = 0; j < 10; ++j) {
                const int q = t + TILE * j, a = q >> 6, t4 = q & 63;
                const int base = bt + 4 * t4;
                unsigned int pack = 0;
                for (int k = 0; k < 4; ++k)
                    if (base + k < NB)
                        pack |= (unsigned)(targets[(size_t)a * NB + base + k] & 1) << (8 * k);
                s_t[0][a * 65 + t4] = pack;
            }
            __syncthreads();
            const unsigned char* st8 = (const unsigned char*)s_t[0];
            const float4* in4t = (const float4*)inputs + (size_t)bt * 10;
            #pragma unroll
            for (int j = 0; j < 10; ++j) {
                const int f = t + TILE * j;
                const int s = f / 10;
                const int r = 4 * (f - s * 10);
                if (bt + s < NB) {
                    const float4 x4 = in4t[f];
                    const float xs[4] = {x4.x, x4.y, x4.z, x4.w};
                    #pragma unroll
                    for (int k = 0; k < 4; ++k) {
                        const float x   = xs[k];
                        const float om  = 1.0f - x;
                        const float w   = s_aw[r + k] * (om * om);
                        const float p   = fmaxf(x,  1e-12f);
                        const float q0  = fmaxf(om, 1e-12f);
                        const float sel = st8[(r + k) * 260 + s] ? p : q0;
                        acc = fmaf(w, __log2f(sel), acc);
                    }
                }
            }
        }
    }

    // ---- reduce: 64-lane shuffle -> cross-wave LDS -> one atomic/block ----
    float vsum = acc;
    #pragma unroll
    for (int off = 32; off > 0; off >>= 1)
        vsum += __shfl_xor(vsum, off, 64);
    if ((t & 63) == 0) s_red[t >> 6] = vsum;
    __syncthreads();
    if (t == 0) {
        float r2 = 0.0f;
        #pragma unroll
        for (int w2 = 0; w2 < TILE / 64; ++w2) r2 += s_red[w2];
        atomicAdd(out, r2);
    }
}

extern "C" void kernel_launch(void* const* d_in, const int* in_sizes, int n_in,
                              void* d_out, int out_size, void* d_ws, size_t ws_size,
                              hipStream_t stream) {
    const float* inputs  = (const float*)d_in[0];
    const int*   targets = (const int*)d_in[1];
    const float* attr_w  = (const float*)d_in[2];
    float* out = (float*)d_out;
    hipMemsetAsync(out, 0, sizeof(float), stream);
    focal_loss_kernel<<<dim3(NBLK), dim3(TILE), 0, stream>>>(inputs, targets, attr_w, out);
}

// Round 6
// 330.364 us; speedup vs baseline: 1.0605x; 1.0605x over previous
//
#include <hip/hip_runtime.h>

#define NB 1000000
#define NA 40
#define BTH 128                        // threads per block == samples per tile
#define NT_FULL (NB / BTH)             // 7812 full tiles
#define TAIL_START (NT_FULL * BTH)     // 999936
#define TAIL_N (NB - TAIL_START)       // 64
#define NBLK 768                       // 3 blocks/CU x 256 CU -> one generation
#define QT (NT_FULL / NBLK)            // 10
#define RT (NT_FULL % NBLK)            // 132 blocks get one extra tile
#define NEG_LN2_OVER_A (-0.017328679513998632f)  // -ln(2)/40 folded into weights

// v6: global_load_lds staging for targets (fire-and-forget, ZERO dest VGPRs).
// R1-R5 established hipcc pins VGPR_Count at 40-64 and either sinks (R1/R3),
// degrades (R4 sched_barrier) or SPILLS (R5: WRITE_SIZE 0.12->46.9 MB) when
// asked to hold load batches in registers -> delivered BW stuck ~2.75 TB/s,
// latency-bound. global_load_lds decouples outstanding-load count from the
// register allocator entirely (Common-mistake #1: compiler never auto-emits).
//  - tile=128 samples, block=128 thr, thread<->sample 1:1.
//  - targets: 20x gll_dwordx4 per tile; per-lane gptr covers attr 2i (lanes
//    0-31) and 2i+1 (lanes 32-63), 16B/lane; LDS linear [40][128] i32, rows
//    512B. Double-buffered (40 KB) -> 3 blocks/CU. No pack phase; compute
//    reads raw labels (consecutive lanes -> 2-way bank access = free, m136).
//  - inputs: per-thread own row, 10x float4, single-buffered regs (40 VGPR,
//    no spill pressure); issued after compute, completed by the barrier's
//    vmcnt(0) drain.
//  - 768 persistent blocks, contiguous tile chunks -> targets stream as
//    sequential runs per attr; 768 atomics total.
// Predicted: dur 116 -> 55-75 us, WRITE_SIZE ~0.12 MB (no spill!), VGPR
// 64-96, occupancy ~19% BY DESIGN (MLP from gll bursts, not waves).
// Tripwires: WRITE_SIZE >> 1 MB = spill returned; dur>110 & hbm~1.4 = gll
// path not engaged; 90-110 us clean = mixed LLC/HBM path wall is real.

typedef __attribute__((address_space(1))) const void gas_t;
typedef __attribute__((address_space(3))) void las_t;

__device__ __forceinline__ void gll16(const void* g, void* l) {
    __builtin_amdgcn_global_load_lds((gas_t*)g, (las_t*)l, 16, 0, 0);
}

__global__ __launch_bounds__(BTH, 2) void focal_loss_kernel(
    const float* __restrict__ inputs,    // [NB, NA] f32
    const int*   __restrict__ targets,   // [NA, NB] i32 in {0,1}
    const float* __restrict__ attr_w,    // [NA] f32
    float* __restrict__ out)             // [1] f32 (pre-zeroed)
{
    __shared__ unsigned int s_t[2][NA * BTH];  // [2][40][128] i32 = 40 KB
    __shared__ float s_aw[NA];
    __shared__ float s_red[BTH / 64];

    const int t = threadIdx.x;
    const int w = t >> 6;                 // wave 0..1
    const int l = t & 63;                 // lane

    if (t < NA) s_aw[t] = attr_w[t] * NEG_LN2_OVER_A;

    const int b  = blockIdx.x;
    const int t0 = b * QT + (b < RT ? b : RT);   // first tile of this block
    const int nt = QT + (b < RT ? 1 : 0);        // full tiles this block

    float acc = 0.0f;
    const float4* in4 = (const float4*)inputs;

    float4 xv[10];

    // ---- prologue: stage tile t0 targets via gll; inputs to regs ----
    {
        const int b0 = t0 * BTH;
        #pragma unroll
        for (int r = 0; r < 10; ++r) {
            const int i = w * 10 + r;             // instr 0..19
            const int a = 2 * i + (l >> 5);       // attr 0..39
            const int s = b0 + 4 * (l & 31);      // 4 samples per lane (16B)
            gll16(targets + (size_t)a * NB + s,
                  (char*)&s_t[0][0] + (size_t)i * 1024);
        }
        #pragma unroll
        for (int j = 0; j < 10; ++j)
            xv[j] = in4[(size_t)(b0 + t) * 10 + j];
    }
    __syncthreads();   // vmcnt(0) drain: tile-0 targets in LDS, xv complete

    int buf = 0;
    for (int it = 0; it < nt; ++it) {
        // ---- stage NEXT tile's targets (fire-and-forget, overlaps compute)
        if (it + 1 < nt) {
            const int b0n = (t0 + it + 1) * BTH;
            #pragma unroll
            for (int r = 0; r < 10; ++r) {
                const int i = w * 10 + r;
                const int a = 2 * i + (l >> 5);
                const int s = b0n + 4 * (l & 31);
                gll16(targets + (size_t)a * NB + s,
                      (char*)&s_t[buf ^ 1][0] + (size_t)i * 1024);
            }
        }

        // ---- compute current tile: thread t == sample (tile*128 + t) ----
        const unsigned int* st = &s_t[buf][0];
        #pragma unroll
        for (int j = 0; j < 10; ++j) {
            const float xs[4] = {xv[j].x, xv[j].y, xv[j].z, xv[j].w};
            #pragma unroll
            for (int k = 0; k < 4; ++k) {
                const int a   = 4 * j + k;
                const float x   = xs[k];
                const float om  = 1.0f - x;
                const float wgt = s_aw[a] * (om * om);   // -ln2/40*aw*(1-x)^2
                const float p   = fmaxf(x,  1e-12f);
                const float q0  = fmaxf(om, 1e-12f);
                const float sel = st[a * BTH + t] ? p : q0;
                acc = fmaf(wgt, __log2f(sel), acc);      // wgt<0, log2<=0
            }
        }

        // ---- next tile's inputs: issued now, completed by barrier drain ---
        if (it + 1 < nt) {
            const int b0n = (t0 + it + 1) * BTH;
            #pragma unroll
            for (int j = 0; j < 10; ++j)
                xv[j] = in4[(size_t)(b0n + t) * 10 + j];
        }
        __syncthreads();   // drains gll(next) + xv(next); swap buffers
        buf ^= 1;
    }

    // ---- global tail: 64 samples, last block only, direct loads ----
    if (b == NBLK - 1 && t < TAIL_N) {
        const int s = TAIL_START + t;
        float4 tx[10];
        #pragma unroll
        for (int j = 0; j < 10; ++j) tx[j] = in4[(size_t)s * 10 + j];
        #pragma unroll
        for (int j = 0; j < 10; ++j) {
            const float xs[4] = {tx[j].x, tx[j].y, tx[j].z, tx[j].w};
            #pragma unroll
            for (int k = 0; k < 4; ++k) {
                const int a   = 4 * j + k;
                const float x   = xs[k];
                const float om  = 1.0f - x;
                const float wgt = s_aw[a] * (om * om);
                const float p   = fmaxf(x,  1e-12f);
                const float q0  = fmaxf(om, 1e-12f);
                const float sel = targets[(size_t)a * NB + s] ? p : q0;
                acc = fmaf(wgt, __log2f(sel), acc);
            }
        }
    }

    // ---- reduce: 64-lane shuffle -> cross-wave LDS -> one atomic/block ----
    float vsum = acc;
    #pragma unroll
    for (int off = 32; off > 0; off >>= 1)
        vsum += __shfl_xor(vsum, off, 64);
    if (l == 0) s_red[w] = vsum;
    __syncthreads();
    if (t == 0) atomicAdd(out, s_red[0] + s_red[1]);
}

extern "C" void kernel_launch(void* const* d_in, const int* in_sizes, int n_in,
                              void* d_out, int out_size, void* d_ws, size_t ws_size,
                              hipStream_t stream) {
    const float* inputs  = (const float*)d_in[0];
    const int*   targets = (const int*)d_in[1];
    const float* attr_w  = (const float*)d_in[2];
    float* out = (float*)d_out;
    hipMemsetAsync(out, 0, sizeof(float), stream);
    focal_loss_kernel<<<dim3(NBLK), dim3(BTH), 0, stream>>>(inputs, targets, attr_w, out);
}